// Round 3
// baseline (2718.471 us; speedup 1.0000x reference)
//
#include <hip/hip_runtime.h>
#include <math.h>

#define B_   8
#define CIN  1152
#define NPTS 4096
#define CH   128
#define KNN  32
#define CHUNK 1024   // rows of D materialized per pass (16 MB)

// ---------------------------------------------------------------------------
// Kernel 1: 1x1 conv (W1 @ x) in FP64 + BN(inference, f64) + LeakyReLU(0.2)
// f = (float)f64. grid: 512 (b = bid&7, ntile = bid>>3), block 256
// ---------------------------------------------------------------------------
__global__ __launch_bounds__(256) void k_conv_bn(
    const float* __restrict__ x, const float* __restrict__ W1,
    const float* __restrict__ gamma, const float* __restrict__ beta,
    const float* __restrict__ bmean, const float* __restrict__ bvar,
    float* __restrict__ f)
{
  __shared__ float Wl[8][132];   // [k][c]
  __shared__ float Xl[8][64];    // [k][n]
  int bid = blockIdx.x;
  int b = bid & 7;
  int nbase = (bid >> 3) * 64;
  int t = threadIdx.x;
  int c0 = (t & 31) * 4, n0 = (t >> 5) * 8;
  double acc[4][8];
#pragma unroll
  for (int i = 0; i < 4; ++i)
#pragma unroll
    for (int j = 0; j < 8; ++j) acc[i][j] = 0.0;

  for (int k0 = 0; k0 < CIN; k0 += 8) {
    {
      int c = t >> 1, kp = (t & 1) * 4;
      float4 w4 = *(const float4*)&W1[(size_t)c * CIN + k0 + kp];
      Wl[kp + 0][c] = w4.x; Wl[kp + 1][c] = w4.y;
      Wl[kp + 2][c] = w4.z; Wl[kp + 3][c] = w4.w;
    }
    {
      int k = t >> 5, n = (t & 31) * 2;
      float2 x2 = *(const float2*)&x[((size_t)b * CIN + (k0 + k)) * NPTS + nbase + n];
      Xl[k][n] = x2.x; Xl[k][n + 1] = x2.y;
    }
    __syncthreads();
#pragma unroll
    for (int kk = 0; kk < 8; ++kk) {
      float4 a  = *(const float4*)&Wl[kk][c0];
      float4 b0 = *(const float4*)&Xl[kk][n0];
      float4 b1 = *(const float4*)&Xl[kk][n0 + 4];
      double av[4] = {(double)a.x, (double)a.y, (double)a.z, (double)a.w};
      double bv[8] = {(double)b0.x, (double)b0.y, (double)b0.z, (double)b0.w,
                      (double)b1.x, (double)b1.y, (double)b1.z, (double)b1.w};
#pragma unroll
      for (int i = 0; i < 4; ++i)
#pragma unroll
        for (int j = 0; j < 8; ++j) acc[i][j] = fma(av[i], bv[j], acc[i][j]);
    }
    __syncthreads();
  }
  double rs[4], gm[4], bt[4], mu[4];
#pragma unroll
  for (int i = 0; i < 4; ++i) {
    int c = c0 + i;
    rs[i] = 1.0 / sqrt((double)bvar[c] + 1e-5);
    gm[i] = (double)gamma[c]; bt[i] = (double)beta[c]; mu[i] = (double)bmean[c];
  }
#pragma unroll
  for (int j = 0; j < 8; ++j) {
    int n = nbase + n0 + j;
    float4 o;
    float* op = &o.x;
#pragma unroll
    for (int i = 0; i < 4; ++i) {
      double v = (acc[i][j] - mu[i]) * rs[i];
      v = v * gm[i] + bt[i];
      if (v < 0.0) v = 0.2 * v;
      op[i] = (float)v;
    }
    *(float4*)&f[((size_t)b * NPTS + n) * CH + c0] = o;
  }
}

// ---------------------------------------------------------------------------
// Kernel 2: sq[row] = sum_c f[row][c]^2 (fp32)
// ---------------------------------------------------------------------------
__global__ __launch_bounds__(256) void k_sq(const float* __restrict__ f,
                                            float* __restrict__ sq)
{
  int row = blockIdx.x * 4 + (threadIdx.x >> 6);
  int lane = threadIdx.x & 63;
  float2 v = ((const float2*)f)[(size_t)row * 64 + lane];
  float s = v.x * v.x + v.y * v.y;
#pragma unroll
  for (int sft = 1; sft < 64; sft <<= 1) s += __shfl_xor(s, sft);
  if (lane == 0) sq[row] = s;
}

// ---------------------------------------------------------------------------
// Kernel 3: M[c][c'] = sum_o Wq[o][c] * Wk[o][c'] ; grid (8,8) x 256
// ---------------------------------------------------------------------------
__global__ __launch_bounds__(256) void k_wqk(const float* __restrict__ Wq,
                                             const float* __restrict__ Wk,
                                             float* __restrict__ M)
{
  __shared__ float Ql[128][17];
  __shared__ float Kl[128][17];
  int t = threadIdx.x;
  int cb = blockIdx.x * 16;
  int db = blockIdx.y * 16;
  {
    int o = t >> 1, h = (t & 1) * 8;
    float4 a = *(const float4*)&Wq[(size_t)o * CH + cb + h];
    float4 b = *(const float4*)&Wq[(size_t)o * CH + cb + h + 4];
    Ql[o][h + 0] = a.x; Ql[o][h + 1] = a.y; Ql[o][h + 2] = a.z; Ql[o][h + 3] = a.w;
    Ql[o][h + 4] = b.x; Ql[o][h + 5] = b.y; Ql[o][h + 6] = b.z; Ql[o][h + 7] = b.w;
    float4 c4 = *(const float4*)&Wk[(size_t)o * CH + db + h];
    float4 d4 = *(const float4*)&Wk[(size_t)o * CH + db + h + 4];
    Kl[o][h + 0] = c4.x; Kl[o][h + 1] = c4.y; Kl[o][h + 2] = c4.z; Kl[o][h + 3] = c4.w;
    Kl[o][h + 4] = d4.x; Kl[o][h + 5] = d4.y; Kl[o][h + 6] = d4.z; Kl[o][h + 7] = d4.w;
  }
  __syncthreads();
  int ci = t >> 4, cj = t & 15;
  float acc = 0.f;
#pragma unroll 8
  for (int o = 0; o < 128; ++o) acc = fmaf(Ql[o][ci], Kl[o][cj], acc);
  M[(size_t)(cb + ci) * CH + db + cj] = acc;
}

// ---------------------------------------------------------------------------
// Kernel 4: qk = f @ M  ([32768 x 128] x [128 x 128]) ; grid 512 x 256
// ---------------------------------------------------------------------------
__global__ __launch_bounds__(256) void k_qk(const float* __restrict__ f,
                                            const float* __restrict__ M,
                                            float* __restrict__ qk)
{
  __shared__ float Ft[128][68];      // [k][r], 64 rows
  __shared__ float Ml[128 * 128];    // [k][c']
  int t = threadIdx.x;
  size_t rbase = (size_t)blockIdx.x * 64;
  {
    int r = t & 63, cp = (t >> 6) * 32;
    for (int i = 0; i < 8; ++i) {
      int c = cp + i * 4;
      float4 v = *(const float4*)&f[(rbase + r) * CH + c];
      Ft[c][r] = v.x; Ft[c + 1][r] = v.y; Ft[c + 2][r] = v.z; Ft[c + 3][r] = v.w;
    }
  }
  {
    const float4* Mg = (const float4*)M;
    float4* Md = (float4*)Ml;
    for (int i = 0; i < 16; ++i) Md[t + 256 * i] = Mg[t + 256 * i];
  }
  __syncthreads();
  int r0 = (t >> 4) * 4, c0 = (t & 15) * 8;
  float acc[4][8];
#pragma unroll
  for (int i = 0; i < 4; ++i)
#pragma unroll
    for (int j = 0; j < 8; ++j) acc[i][j] = 0.f;
#pragma unroll 8
  for (int k = 0; k < 128; ++k) {
    float4 a  = *(const float4*)&Ft[k][r0];
    float4 b0 = *(const float4*)&Ml[k * 128 + c0];
    float4 b1 = *(const float4*)&Ml[k * 128 + c0 + 4];
    float av[4] = {a.x, a.y, a.z, a.w};
    float bv[8] = {b0.x, b0.y, b0.z, b0.w, b1.x, b1.y, b1.z, b1.w};
#pragma unroll
    for (int i = 0; i < 4; ++i)
#pragma unroll
      for (int j = 0; j < 8; ++j) acc[i][j] = fmaf(av[i], bv[j], acc[i][j]);
  }
#pragma unroll
  for (int i = 0; i < 4; ++i) {
    float4 o0 = {acc[i][0], acc[i][1], acc[i][2], acc[i][3]};
    float4 o1 = {acc[i][4], acc[i][5], acc[i][6], acc[i][7]};
    *(float4*)&qk[(rbase + r0 + i) * CH + c0]     = o0;
    *(float4*)&qk[(rbase + r0 + i) * CH + c0 + 4] = o1;
  }
}

// ---------------------------------------------------------------------------
// Kernel 5: distance GEMM -> D[chunk-local row][m] = (sq_n + sq_m) - 2 f_n.f_m
// grid (CHUNK/64, 64), block 256; batch b, rows [rowoff, rowoff+CHUNK)
// ---------------------------------------------------------------------------
__global__ __launch_bounds__(256) void k_dist(
    const float* __restrict__ f, const float* __restrict__ sq,
    float* __restrict__ D, int b, int rowoff)
{
  __shared__ float As[128][68];
  __shared__ float Bs[128][68];
  int t = threadIdx.x;
  int nb = rowoff + blockIdx.x * 64;      // batch-local row base
  int mb = blockIdx.y * 64;               // batch-local col base
  const float* fb = f + (size_t)b * NPTS * CH;
  {
    int r = t & 63, cq = (t >> 6) * 32;
    for (int i = 0; i < 8; ++i) {
      int c = cq + i * 4;
      float4 v = *(const float4*)&fb[(size_t)(nb + r) * CH + c];
      As[c][r] = v.x; As[c + 1][r] = v.y; As[c + 2][r] = v.z; As[c + 3][r] = v.w;
      float4 u = *(const float4*)&fb[(size_t)(mb + r) * CH + c];
      Bs[c][r] = u.x; Bs[c + 1][r] = u.y; Bs[c + 2][r] = u.z; Bs[c + 3][r] = u.w;
    }
  }
  __syncthreads();
  int r0 = (t >> 4) * 4, m0 = (t & 15) * 4;
  float acc[4][4];
#pragma unroll
  for (int i = 0; i < 4; ++i)
#pragma unroll
    for (int j = 0; j < 4; ++j) acc[i][j] = 0.f;
#pragma unroll 8
  for (int c = 0; c < 128; ++c) {
    float4 a  = *(const float4*)&As[c][r0];
    float4 bb = *(const float4*)&Bs[c][m0];
    float av[4] = {a.x, a.y, a.z, a.w};
    float bv[4] = {bb.x, bb.y, bb.z, bb.w};
#pragma unroll
    for (int i = 0; i < 4; ++i)
#pragma unroll
      for (int j = 0; j < 4; ++j) acc[i][j] = fmaf(av[i], bv[j], acc[i][j]);
  }
  float sqm[4];
#pragma unroll
  for (int j = 0; j < 4; ++j) sqm[j] = sq[(size_t)b * NPTS + mb + m0 + j];
#pragma unroll
  for (int i = 0; i < 4; ++i) {
    float sqn = sq[(size_t)b * NPTS + nb + r0 + i];
    float4 o;
    o.x = (sqn + sqm[0]) - 2.f * acc[i][0];
    o.y = (sqn + sqm[1]) - 2.f * acc[i][1];
    o.z = (sqn + sqm[2]) - 2.f * acc[i][2];
    o.w = (sqn + sqm[3]) - 2.f * acc[i][3];
    int rloc = blockIdx.x * 64 + r0 + i;    // chunk-local row
    *(float4*)&D[(size_t)rloc * NPTS + mb + m0] = o;
  }
}

// ---------------------------------------------------------------------------
// Kernel 6: exact stable top-32 per row (serial min-extraction, lexicographic
// (value, index) — matches jax.lax.top_k stability) + attention + std-over-K
// grid CHUNK, block 256; one block per point.
// ---------------------------------------------------------------------------
__global__ __launch_bounds__(256) void k_select(
    const float* __restrict__ D, const float* __restrict__ f,
    const float* __restrict__ qk, float* __restrict__ sv,
    int b, int rowoff)
{
  __shared__ float Drow[NPTS];
  __shared__ float redv[4];
  __shared__ int   redi[4];
  __shared__ int   kept[KNN];
  __shared__ float qkl[CH];
  __shared__ float fc[CH];
  __shared__ float eng[KNN];

  int t = threadIdx.x;
  int row = rowoff + blockIdx.x;            // batch-local row
  const float* fb = f + (size_t)b * NPTS * CH;
  {
    const float4* Dp = (const float4*)(D + (size_t)blockIdx.x * NPTS);
    float4* Dl = (float4*)Drow;
#pragma unroll
    for (int i = 0; i < 4; ++i) Dl[t + 256 * i] = Dp[t + 256 * i];
  }
  if (t < 32) {
    ((float4*)qkl)[t] = ((const float4*)(qk + ((size_t)b * NPTS + row) * CH))[t];
  } else if (t < 64) {
    ((float4*)fc)[t - 32] = ((const float4*)(fb + (size_t)row * CH))[t - 32];
  }
  __syncthreads();

  // 32 serial stable min-extractions
  for (int k = 0; k < KNN; ++k) {
    float bv = INFINITY; int bidx = 0x7fffffff;
#pragma unroll
    for (int i = 0; i < 16; ++i) {
      int idx = t + 256 * i;                // strictly increasing per thread
      float v = Drow[idx];
      if (v < bv) { bv = v; bidx = idx; }   // strict <: first (lowest) idx kept
    }
#pragma unroll
    for (int m = 1; m < 64; m <<= 1) {
      float ov = __shfl_xor(bv, m);
      int   oi = __shfl_xor(bidx, m);
      if (ov < bv || (ov == bv && oi < bidx)) { bv = ov; bidx = oi; }
    }
    if ((t & 63) == 0) { redv[t >> 6] = bv; redi[t >> 6] = bidx; }
    __syncthreads();
    if (t == 0) {
      float fv = redv[0]; int fi = redi[0];
#pragma unroll
      for (int w = 1; w < 4; ++w)
        if (redv[w] < fv || (redv[w] == fv && redi[w] < fi)) { fv = redv[w]; fi = redi[w]; }
      kept[k] = fi;
      Drow[fi] = INFINITY;
    }
    __syncthreads();
  }

  // energies: e_k = qk_n . (f_m - f_n) / sqrt(128)
  {
    int kk = t >> 3, lg = t & 7;
    int mg = kept[kk];
    const float* fm = fb + (size_t)mg * CH;
    float dd = 0.f, ds = 0.f;
#pragma unroll
    for (int i = 0; i < 4; ++i) {
      float4 qv = *(const float4*)&qkl[lg * 16 + i * 4];
      float4 vm = *(const float4*)&fm[lg * 16 + i * 4];
      float4 vc = *(const float4*)&fc[lg * 16 + i * 4];
      dd = fmaf(qv.x, vm.x, dd); dd = fmaf(qv.y, vm.y, dd);
      dd = fmaf(qv.z, vm.z, dd); dd = fmaf(qv.w, vm.w, dd);
      ds = fmaf(qv.x, vc.x, ds); ds = fmaf(qv.y, vc.y, ds);
      ds = fmaf(qv.z, vc.z, ds); ds = fmaf(qv.w, vc.w, ds);
    }
#pragma unroll
    for (int m = 1; m < 8; m <<= 1) { dd += __shfl_xor(dd, m); ds += __shfl_xor(ds, m); }
    if (lg == 0) eng[kk] = (dd - ds) * 0.08838834764831845f;
  }
  __syncthreads();

  // softmax over K + biased std over K (wave 0, lanes 0..31)
  if (t < 64) {
    float e = (t < 32) ? eng[t] : -INFINITY;
    float mx = e;
#pragma unroll
    for (int m = 1; m < 32; m <<= 1) mx = fmaxf(mx, __shfl_xor(mx, m));
    float ex = (t < 32) ? expf(e - mx) : 0.f;
    float sm = ex;
#pragma unroll
    for (int m = 1; m < 32; m <<= 1) sm += __shfl_xor(sm, m);
    float a  = (t < 32) ? (ex / sm) : 0.f;
    float sa = a;
#pragma unroll
    for (int m = 1; m < 32; m <<= 1) sa += __shfl_xor(sa, m);
    float mean = sa * (1.f / 32.f);
    float dv = (t < 32) ? (a - mean) : 0.f;
    float vr = dv * dv;
#pragma unroll
    for (int m = 1; m < 32; m <<= 1) vr += __shfl_xor(vr, m);
    if (t == 0) sv[(size_t)b * NPTS + row] = sqrtf(vr * (1.f / 32.f));
  }
}

// ---------------------------------------------------------------------------
// Kernel 7: per-cloud standardize (ddof=1) + modified sigmoid; grid 8 x 256
// ---------------------------------------------------------------------------
__global__ __launch_bounds__(256) void k_final(const float* __restrict__ s,
                                               float* __restrict__ out)
{
  __shared__ float red[4];
  int b = blockIdx.x, t = threadIdx.x;
  const float4* sp = (const float4*)(s + (size_t)b * NPTS);
  float4* op = (float4*)(out + (size_t)b * NPTS);
  float4 vs[4];
  float loc = 0.f;
#pragma unroll
  for (int i = 0; i < 4; ++i) {
    vs[i] = sp[t + 256 * i];
    loc += vs[i].x + vs[i].y + vs[i].z + vs[i].w;
  }
#pragma unroll
  for (int sft = 1; sft < 64; sft <<= 1) loc += __shfl_xor(loc, sft);
  if ((t & 63) == 0) red[t >> 6] = loc;
  __syncthreads();
  float meanv = (red[0] + red[1] + red[2] + red[3]) * (1.f / 4096.f);
  __syncthreads();
  float loc2 = 0.f;
#pragma unroll
  for (int i = 0; i < 4; ++i) {
    float dx = vs[i].x - meanv, dy = vs[i].y - meanv;
    float dz = vs[i].z - meanv, dw = vs[i].w - meanv;
    loc2 += dx * dx + dy * dy + dz * dz + dw * dw;
  }
#pragma unroll
  for (int sft = 1; sft < 64; sft <<= 1) loc2 += __shfl_xor(loc2, sft);
  if ((t & 63) == 0) red[t >> 6] = loc2;
  __syncthreads();
  float var = (red[0] + red[1] + red[2] + red[3]) * (1.f / 4095.f);
  float rstd = rsqrtf(var);
  const float L20 = 4.3219280948873623f;  // log2(20)
#pragma unroll
  for (int i = 0; i < 4; ++i) {
    float4 v = vs[i], o;
    o.x = 1.f / (1.f + exp2f(-(v.x - meanv) * rstd * L20));
    o.y = 1.f / (1.f + exp2f(-(v.y - meanv) * rstd * L20));
    o.z = 1.f / (1.f + exp2f(-(v.z - meanv) * rstd * L20));
    o.w = 1.f / (1.f + exp2f(-(v.w - meanv) * rstd * L20));
    op[t + 256 * i] = o;
  }
}

// ---------------------------------------------------------------------------
extern "C" void kernel_launch(void* const* d_in, const int* in_sizes, int n_in,
                              void* d_out, int out_size, void* d_ws, size_t ws_size,
                              hipStream_t stream)
{
  const float* x     = (const float*)d_in[0];
  const float* W1    = (const float*)d_in[1];
  const float* gamma = (const float*)d_in[2];
  const float* beta  = (const float*)d_in[3];
  const float* bmean = (const float*)d_in[4];
  const float* bvar  = (const float*)d_in[5];
  const float* Wq    = (const float*)d_in[6];
  const float* Wk    = (const float*)d_in[7];
  float* out = (float*)d_out;

  float* f  = (float*)d_ws;                               // 8*4096*128   = 16 MB
  float* qk = f  + (size_t)B_ * NPTS * CH;                // 16 MB
  float* sq = qk + (size_t)B_ * NPTS * CH;                // 128 KB
  float* sv = sq + (size_t)B_ * NPTS;                     // 128 KB
  float* M  = sv + (size_t)B_ * NPTS;                     // 64 KB
  float* D  = M  + (size_t)CH * CH;                       // CHUNK*4096*4 = 16 MB

  hipLaunchKernelGGL(k_conv_bn, dim3(512), dim3(256), 0, stream,
                     x, W1, gamma, beta, bmean, bvar, f);
  hipLaunchKernelGGL(k_sq, dim3(8192), dim3(256), 0, stream, f, sq);
  hipLaunchKernelGGL(k_wqk, dim3(8, 8), dim3(256), 0, stream, Wq, Wk, M);
  hipLaunchKernelGGL(k_qk, dim3(512), dim3(256), 0, stream, f, M, qk);
  for (int b = 0; b < B_; ++b) {
    for (int ro = 0; ro < NPTS; ro += CHUNK) {
      hipLaunchKernelGGL(k_dist, dim3(CHUNK / 64, 64), dim3(256), 0, stream,
                         f, sq, D, b, ro);
      hipLaunchKernelGGL(k_select, dim3(CHUNK), dim3(256), 0, stream,
                         D, f, qk, sv, b, ro);
    }
  }
  hipLaunchKernelGGL(k_final, dim3(8), dim3(256), 0, stream, sv, out);
}

// Round 5
// 2145.171 us; speedup vs baseline: 1.2673x; 1.2673x over previous
//
#include <hip/hip_runtime.h>
#include <math.h>

#define B_   8
#define CIN  1152
#define NPTS 4096
#define CH   128
#define KNN  32
#define CHUNK 1024   // rows of D materialized per pass (16 MB)

// ---------------------------------------------------------------------------
// Kernel 1: 1x1 conv (W1 @ x) in FP64 + BN(inference, f64) + LeakyReLU(0.2)
// f = (float)f64. grid: 512 (b = bid&7, ntile = bid>>3), block 256
// [round-3 verbatim — exactly-rounded f is required by the fragile KNN
//  boundary point; both fp32 conv variants flipped it]
// ---------------------------------------------------------------------------
__global__ __launch_bounds__(256) void k_conv_bn(
    const float* __restrict__ x, const float* __restrict__ W1,
    const float* __restrict__ gamma, const float* __restrict__ beta,
    const float* __restrict__ bmean, const float* __restrict__ bvar,
    float* __restrict__ f)
{
  __shared__ float Wl[8][132];   // [k][c]
  __shared__ float Xl[8][64];    // [k][n]
  int bid = blockIdx.x;
  int b = bid & 7;
  int nbase = (bid >> 3) * 64;
  int t = threadIdx.x;
  int c0 = (t & 31) * 4, n0 = (t >> 5) * 8;
  double acc[4][8];
#pragma unroll
  for (int i = 0; i < 4; ++i)
#pragma unroll
    for (int j = 0; j < 8; ++j) acc[i][j] = 0.0;

  for (int k0 = 0; k0 < CIN; k0 += 8) {
    {
      int c = t >> 1, kp = (t & 1) * 4;
      float4 w4 = *(const float4*)&W1[(size_t)c * CIN + k0 + kp];
      Wl[kp + 0][c] = w4.x; Wl[kp + 1][c] = w4.y;
      Wl[kp + 2][c] = w4.z; Wl[kp + 3][c] = w4.w;
    }
    {
      int k = t >> 5, n = (t & 31) * 2;
      float2 x2 = *(const float2*)&x[((size_t)b * CIN + (k0 + k)) * NPTS + nbase + n];
      Xl[k][n] = x2.x; Xl[k][n + 1] = x2.y;
    }
    __syncthreads();
#pragma unroll
    for (int kk = 0; kk < 8; ++kk) {
      float4 a  = *(const float4*)&Wl[kk][c0];
      float4 b0 = *(const float4*)&Xl[kk][n0];
      float4 b1 = *(const float4*)&Xl[kk][n0 + 4];
      double av[4] = {(double)a.x, (double)a.y, (double)a.z, (double)a.w};
      double bv[8] = {(double)b0.x, (double)b0.y, (double)b0.z, (double)b0.w,
                      (double)b1.x, (double)b1.y, (double)b1.z, (double)b1.w};
#pragma unroll
      for (int i = 0; i < 4; ++i)
#pragma unroll
        for (int j = 0; j < 8; ++j) acc[i][j] = fma(av[i], bv[j], acc[i][j]);
    }
    __syncthreads();
  }
  double rs[4], gm[4], bt[4], mu[4];
#pragma unroll
  for (int i = 0; i < 4; ++i) {
    int c = c0 + i;
    rs[i] = 1.0 / sqrt((double)bvar[c] + 1e-5);
    gm[i] = (double)gamma[c]; bt[i] = (double)beta[c]; mu[i] = (double)bmean[c];
  }
#pragma unroll
  for (int j = 0; j < 8; ++j) {
    int n = nbase + n0 + j;
    float4 o;
    float* op = &o.x;
#pragma unroll
    for (int i = 0; i < 4; ++i) {
      double v = (acc[i][j] - mu[i]) * rs[i];
      v = v * gm[i] + bt[i];
      if (v < 0.0) v = 0.2 * v;
      op[i] = (float)v;
    }
    *(float4*)&f[((size_t)b * NPTS + n) * CH + c0] = o;
  }
}

// ---------------------------------------------------------------------------
// Kernel 2: sq[row] = sum_c f[row][c]^2 (fp32)  [round-3 verbatim]
// ---------------------------------------------------------------------------
__global__ __launch_bounds__(256) void k_sq(const float* __restrict__ f,
                                            float* __restrict__ sq)
{
  int row = blockIdx.x * 4 + (threadIdx.x >> 6);
  int lane = threadIdx.x & 63;
  float2 v = ((const float2*)f)[(size_t)row * 64 + lane];
  float s = v.x * v.x + v.y * v.y;
#pragma unroll
  for (int sft = 1; sft < 64; sft <<= 1) s += __shfl_xor(s, sft);
  if (lane == 0) sq[row] = s;
}

// ---------------------------------------------------------------------------
// Kernel 3: M[c][c'] = sum_o Wq[o][c] * Wk[o][c'] ; grid (8,8) x 256
// ---------------------------------------------------------------------------
__global__ __launch_bounds__(256) void k_wqk(const float* __restrict__ Wq,
                                             const float* __restrict__ Wk,
                                             float* __restrict__ M)
{
  __shared__ float Ql[128][17];
  __shared__ float Kl[128][17];
  int t = threadIdx.x;
  int cb = blockIdx.x * 16;
  int db = blockIdx.y * 16;
  {
    int o = t >> 1, h = (t & 1) * 8;
    float4 a = *(const float4*)&Wq[(size_t)o * CH + cb + h];
    float4 b = *(const float4*)&Wq[(size_t)o * CH + cb + h + 4];
    Ql[o][h + 0] = a.x; Ql[o][h + 1] = a.y; Ql[o][h + 2] = a.z; Ql[o][h + 3] = a.w;
    Ql[o][h + 4] = b.x; Ql[o][h + 5] = b.y; Ql[o][h + 6] = b.z; Ql[o][h + 7] = b.w;
    float4 c4 = *(const float4*)&Wk[(size_t)o * CH + db + h];
    float4 d4 = *(const float4*)&Wk[(size_t)o * CH + db + h + 4];
    Kl[o][h + 0] = c4.x; Kl[o][h + 1] = c4.y; Kl[o][h + 2] = c4.z; Kl[o][h + 3] = c4.w;
    Kl[o][h + 4] = d4.x; Kl[o][h + 5] = d4.y; Kl[o][h + 6] = d4.z; Kl[o][h + 7] = d4.w;
  }
  __syncthreads();
  int ci = t >> 4, cj = t & 15;
  float acc = 0.f;
#pragma unroll 8
  for (int o = 0; o < 128; ++o) acc = fmaf(Ql[o][ci], Kl[o][cj], acc);
  M[(size_t)(cb + ci) * CH + db + cj] = acc;
}

// ---------------------------------------------------------------------------
// Kernel 4: qk = f @ M  ([32768 x 128] x [128 x 128]) ; grid 512 x 256
// ---------------------------------------------------------------------------
__global__ __launch_bounds__(256) void k_qk(const float* __restrict__ f,
                                            const float* __restrict__ M,
                                            float* __restrict__ qk)
{
  __shared__ float Ft[128][68];      // [k][r], 64 rows
  __shared__ float Ml[128 * 128];    // [k][c']
  int t = threadIdx.x;
  size_t rbase = (size_t)blockIdx.x * 64;
  {
    int r = t & 63, cp = (t >> 6) * 32;
    for (int i = 0; i < 8; ++i) {
      int c = cp + i * 4;
      float4 v = *(const float4*)&f[(rbase + r) * CH + c];
      Ft[c][r] = v.x; Ft[c + 1][r] = v.y; Ft[c + 2][r] = v.z; Ft[c + 3][r] = v.w;
    }
  }
  {
    const float4* Mg = (const float4*)M;
    float4* Md = (float4*)Ml;
    for (int i = 0; i < 16; ++i) Md[t + 256 * i] = Mg[t + 256 * i];
  }
  __syncthreads();
  int r0 = (t >> 4) * 4, c0 = (t & 15) * 8;
  float acc[4][8];
#pragma unroll
  for (int i = 0; i < 4; ++i)
#pragma unroll
    for (int j = 0; j < 8; ++j) acc[i][j] = 0.f;
#pragma unroll 8
  for (int k = 0; k < 128; ++k) {
    float4 a  = *(const float4*)&Ft[k][r0];
    float4 b0 = *(const float4*)&Ml[k * 128 + c0];
    float4 b1 = *(const float4*)&Ml[k * 128 + c0 + 4];
    float av[4] = {a.x, a.y, a.z, a.w};
    float bv[8] = {b0.x, b0.y, b0.z, b0.w, b1.x, b1.y, b1.z, b1.w};
#pragma unroll
    for (int i = 0; i < 4; ++i)
#pragma unroll
      for (int j = 0; j < 8; ++j) acc[i][j] = fmaf(av[i], bv[j], acc[i][j]);
  }
#pragma unroll
  for (int i = 0; i < 4; ++i) {
    float4 o0 = {acc[i][0], acc[i][1], acc[i][2], acc[i][3]};
    float4 o1 = {acc[i][4], acc[i][5], acc[i][6], acc[i][7]};
    *(float4*)&qk[(rbase + r0 + i) * CH + c0]     = o0;
    *(float4*)&qk[(rbase + r0 + i) * CH + c0 + 4] = o1;
  }
}

// ---------------------------------------------------------------------------
// Kernel 5: distance GEMM -> D[chunk-local row][m] = (sq_n + sq_m) - 2 f_n.f_m
// [round-3 verbatim — D's exact accumulation order is part of the passing
//  numeric recipe]
// ---------------------------------------------------------------------------
__global__ __launch_bounds__(256) void k_dist(
    const float* __restrict__ f, const float* __restrict__ sq,
    float* __restrict__ D, int b, int rowoff)
{
  __shared__ float As[128][68];
  __shared__ float Bs[128][68];
  int t = threadIdx.x;
  int nb = rowoff + blockIdx.x * 64;      // batch-local row base
  int mb = blockIdx.y * 64;               // batch-local col base
  const float* fb = f + (size_t)b * NPTS * CH;
  {
    int r = t & 63, cq = (t >> 6) * 32;
    for (int i = 0; i < 8; ++i) {
      int c = cq + i * 4;
      float4 v = *(const float4*)&fb[(size_t)(nb + r) * CH + c];
      As[c][r] = v.x; As[c + 1][r] = v.y; As[c + 2][r] = v.z; As[c + 3][r] = v.w;
      float4 u = *(const float4*)&fb[(size_t)(mb + r) * CH + c];
      Bs[c][r] = u.x; Bs[c + 1][r] = u.y; Bs[c + 2][r] = u.z; Bs[c + 3][r] = u.w;
    }
  }
  __syncthreads();
  int r0 = (t >> 4) * 4, m0 = (t & 15) * 4;
  float acc[4][4];
#pragma unroll
  for (int i = 0; i < 4; ++i)
#pragma unroll
    for (int j = 0; j < 4; ++j) acc[i][j] = 0.f;
#pragma unroll 8
  for (int c = 0; c < 128; ++c) {
    float4 a  = *(const float4*)&As[c][r0];
    float4 bb = *(const float4*)&Bs[c][m0];
    float av[4] = {a.x, a.y, a.z, a.w};
    float bv[4] = {bb.x, bb.y, bb.z, bb.w};
#pragma unroll
    for (int i = 0; i < 4; ++i)
#pragma unroll
      for (int j = 0; j < 4; ++j) acc[i][j] = fmaf(av[i], bv[j], acc[i][j]);
  }
  float sqm[4];
#pragma unroll
  for (int j = 0; j < 4; ++j) sqm[j] = sq[(size_t)b * NPTS + mb + m0 + j];
#pragma unroll
  for (int i = 0; i < 4; ++i) {
    float sqn = sq[(size_t)b * NPTS + nb + r0 + i];
    float4 o;
    o.x = (sqn + sqm[0]) - 2.f * acc[i][0];
    o.y = (sqn + sqm[1]) - 2.f * acc[i][1];
    o.z = (sqn + sqm[2]) - 2.f * acc[i][2];
    o.w = (sqn + sqm[3]) - 2.f * acc[i][3];
    int rloc = blockIdx.x * 64 + r0 + i;    // chunk-local row
    *(float4*)&D[(size_t)rloc * NPTS + mb + m0] = o;
  }
}

// ---------------------------------------------------------------------------
// Kernel 6: radix-select exact top-32. Set = {keys < thr_key} ∪ lowest-index
// {keys == thr_key} — identical to round-3's stable extraction set given
// identical keys. + attention + std-over-K. grid CHUNK, block 256.
// ---------------------------------------------------------------------------
__device__ __forceinline__ unsigned int sortkey(float x) {
  unsigned int u = __float_as_uint(x);
  return (u & 0x80000000u) ? ~u : (u | 0x80000000u);
}

__global__ __launch_bounds__(256) void k_select(
    const float* __restrict__ D, const float* __restrict__ f,
    const float* __restrict__ qk, float* __restrict__ sv,
    int b, int rowoff)
{
  __shared__ unsigned int keys[NPTS];      // 16 KB sortable keys
  __shared__ unsigned int hist[256];
  __shared__ unsigned int wsum[4];
  __shared__ unsigned int eqw[4];
  __shared__ unsigned int sh_bucket, sh_excl, nkept;
  __shared__ int   kept[KNN];
  __shared__ float qkl[CH];
  __shared__ float fc[CH];
  __shared__ float eng[KNN];

  int t = threadIdx.x;
  int row = rowoff + blockIdx.x;            // batch-local row
  const float* fb = f + (size_t)b * NPTS * CH;

  {
    const float4* Dp = (const float4*)(D + (size_t)blockIdx.x * NPTS);
#pragma unroll
    for (int i = 0; i < 4; ++i) {
      float4 v = Dp[t + 256 * i];
      uint4 u;
      u.x = sortkey(v.x); u.y = sortkey(v.y);
      u.z = sortkey(v.z); u.w = sortkey(v.w);
      ((uint4*)keys)[t + 256 * i] = u;
    }
  }
  if (t == 0) nkept = 0;
  if (t < 32) {
    ((float4*)qkl)[t] = ((const float4*)(qk + ((size_t)b * NPTS + row) * CH))[t];
  } else if (t < 64) {
    ((float4*)fc)[t - 32] = ((const float4*)(fb + (size_t)row * CH))[t - 32];
  }
  __syncthreads();

  // 4-pass 8-bit radix select: find exact key of rank KNN (1-based)
  unsigned int prefix = 0;
  unsigned int target = KNN;
  unsigned int cnt_less = 0;
  for (int pass = 0; pass < 4; ++pass) {
    int shift = 24 - pass * 8;
    hist[t] = 0;
    __syncthreads();
#pragma unroll
    for (int i = 0; i < 16; ++i) {
      unsigned int k = keys[t + 256 * i];
      bool m = (pass == 0) || ((k >> (shift + 8)) == prefix);
      if (m) atomicAdd(&hist[(k >> shift) & 255u], 1u);
    }
    __syncthreads();
    unsigned int v = hist[t];
    unsigned int sc = v;
#pragma unroll
    for (int d = 1; d < 64; d <<= 1) {
      unsigned int nn = __shfl_up(sc, d);
      if ((t & 63) >= d) sc += nn;
    }
    if ((t & 63) == 63) wsum[t >> 6] = sc;
    __syncthreads();
    unsigned int wo = 0;
#pragma unroll
    for (int w = 0; w < 4; ++w) wo += (w < (t >> 6)) ? wsum[w] : 0u;
    unsigned int incl = sc + wo;
    unsigned int excl = incl - v;
    if (excl < target && target <= incl) { sh_bucket = (unsigned int)t; sh_excl = excl; }
    __syncthreads();
    prefix = (prefix << 8) | sh_bucket;
    target -= sh_excl;
    cnt_less += sh_excl;
    __syncthreads();
  }
  unsigned int thr_key = prefix;

  // compact strictly-less (arbitrary slot order; set semantics)
#pragma unroll
  for (int i = 0; i < 16; ++i) {
    int idx = t + 256 * i;
    if (keys[idx] < thr_key) {
      unsigned int p = atomicAdd(&nkept, 1u);
      kept[p] = idx;
    }
  }
  // fill remaining slots with ==thr_key elements in increasing index order
  {
    unsigned int eqloc = 0;
#pragma unroll
    for (int j = 0; j < 16; ++j) eqloc += (keys[t * 16 + j] == thr_key) ? 1u : 0u;
    unsigned int esc = eqloc;
#pragma unroll
    for (int d = 1; d < 64; d <<= 1) {
      unsigned int nn = __shfl_up(esc, d);
      if ((t & 63) >= d) esc += nn;
    }
    if ((t & 63) == 63) eqw[t >> 6] = esc;
    __syncthreads();
    unsigned int ewo = 0;
#pragma unroll
    for (int w = 0; w < 4; ++w) ewo += (w < (t >> 6)) ? eqw[w] : 0u;
    unsigned int slot = cnt_less + (esc + ewo - eqloc);
#pragma unroll
    for (int j = 0; j < 16; ++j) {
      if (keys[t * 16 + j] == thr_key) {
        if (slot < KNN) kept[slot] = t * 16 + j;
        slot++;
      }
    }
  }
  __syncthreads();

  // energies: e_k = qk_n . (f_m - f_n) / sqrt(128)
  {
    int kk = t >> 3, lg = t & 7;
    int mg = kept[kk];
    const float* fm = fb + (size_t)mg * CH;
    float dd = 0.f, ds = 0.f;
#pragma unroll
    for (int i = 0; i < 4; ++i) {
      float4 qv = *(const float4*)&qkl[lg * 16 + i * 4];
      float4 vm = *(const float4*)&fm[lg * 16 + i * 4];
      float4 vc = *(const float4*)&fc[lg * 16 + i * 4];
      dd = fmaf(qv.x, vm.x, dd); dd = fmaf(qv.y, vm.y, dd);
      dd = fmaf(qv.z, vm.z, dd); dd = fmaf(qv.w, vm.w, dd);
      ds = fmaf(qv.x, vc.x, ds); ds = fmaf(qv.y, vc.y, ds);
      ds = fmaf(qv.z, vc.z, ds); ds = fmaf(qv.w, vc.w, ds);
    }
#pragma unroll
    for (int m = 1; m < 8; m <<= 1) { dd += __shfl_xor(dd, m); ds += __shfl_xor(ds, m); }
    if (lg == 0) eng[kk] = (dd - ds) * 0.08838834764831845f;
  }
  __syncthreads();

  // softmax over K + biased std over K (lanes 0..31 of wave 0)
  if (t < 64) {
    float e = (t < 32) ? eng[t] : -INFINITY;
    float mx = e;
#pragma unroll
    for (int m = 1; m < 32; m <<= 1) mx = fmaxf(mx, __shfl_xor(mx, m));
    float ex = (t < 32) ? expf(e - mx) : 0.f;
    float sm = ex;
#pragma unroll
    for (int m = 1; m < 32; m <<= 1) sm += __shfl_xor(sm, m);
    float a  = (t < 32) ? (ex / sm) : 0.f;
    float sa = a;
#pragma unroll
    for (int m = 1; m < 32; m <<= 1) sa += __shfl_xor(sa, m);
    float mean = sa * (1.f / 32.f);
    float dv = (t < 32) ? (a - mean) : 0.f;
    float vr = dv * dv;
#pragma unroll
    for (int m = 1; m < 32; m <<= 1) vr += __shfl_xor(vr, m);
    if (t == 0) sv[(size_t)b * NPTS + row] = sqrtf(vr * (1.f / 32.f));
  }
}

// ---------------------------------------------------------------------------
// Kernel 7: per-cloud standardize (ddof=1) + modified sigmoid; grid 8 x 256
// ---------------------------------------------------------------------------
__global__ __launch_bounds__(256) void k_final(const float* __restrict__ s,
                                               float* __restrict__ out)
{
  __shared__ float red[4];
  int b = blockIdx.x, t = threadIdx.x;
  const float4* sp = (const float4*)(s + (size_t)b * NPTS);
  float4* op = (float4*)(out + (size_t)b * NPTS);
  float4 vs[4];
  float loc = 0.f;
#pragma unroll
  for (int i = 0; i < 4; ++i) {
    vs[i] = sp[t + 256 * i];
    loc += vs[i].x + vs[i].y + vs[i].z + vs[i].w;
  }
#pragma unroll
  for (int sft = 1; sft < 64; sft <<= 1) loc += __shfl_xor(loc, sft);
  if ((t & 63) == 0) red[t >> 6] = loc;
  __syncthreads();
  float meanv = (red[0] + red[1] + red[2] + red[3]) * (1.f / 4096.f);
  __syncthreads();
  float loc2 = 0.f;
#pragma unroll
  for (int i = 0; i < 4; ++i) {
    float dx = vs[i].x - meanv, dy = vs[i].y - meanv;
    float dz = vs[i].z - meanv, dw = vs[i].w - meanv;
    loc2 += dx * dx + dy * dy + dz * dz + dw * dw;
  }
#pragma unroll
  for (int sft = 1; sft < 64; sft <<= 1) loc2 += __shfl_xor(loc2, sft);
  if ((t & 63) == 0) red[t >> 6] = loc2;
  __syncthreads();
  float var = (red[0] + red[1] + red[2] + red[3]) * (1.f / 4095.f);
  float rstd = rsqrtf(var);
  const float L20 = 4.3219280948873623f;  // log2(20)
#pragma unroll
  for (int i = 0; i < 4; ++i) {
    float4 v = vs[i], o;
    o.x = 1.f / (1.f + exp2f(-(v.x - meanv) * rstd * L20));
    o.y = 1.f / (1.f + exp2f(-(v.y - meanv) * rstd * L20));
    o.z = 1.f / (1.f + exp2f(-(v.z - meanv) * rstd * L20));
    o.w = 1.f / (1.f + exp2f(-(v.w - meanv) * rstd * L20));
    op[t + 256 * i] = o;
  }
}

// ---------------------------------------------------------------------------
extern "C" void kernel_launch(void* const* d_in, const int* in_sizes, int n_in,
                              void* d_out, int out_size, void* d_ws, size_t ws_size,
                              hipStream_t stream)
{
  const float* x     = (const float*)d_in[0];
  const float* W1    = (const float*)d_in[1];
  const float* gamma = (const float*)d_in[2];
  const float* beta  = (const float*)d_in[3];
  const float* bmean = (const float*)d_in[4];
  const float* bvar  = (const float*)d_in[5];
  const float* Wq    = (const float*)d_in[6];
  const float* Wk    = (const float*)d_in[7];
  float* out = (float*)d_out;

  float* f  = (float*)d_ws;                               // 16 MB
  float* qk = f  + (size_t)B_ * NPTS * CH;                // 16 MB
  float* sq = qk + (size_t)B_ * NPTS * CH;                // 128 KB
  float* sv = sq + (size_t)B_ * NPTS;                     // 128 KB
  float* M  = sv + (size_t)B_ * NPTS;                     // 64 KB
  float* D  = M  + (size_t)CH * CH;                       // 16 MB

  hipLaunchKernelGGL(k_conv_bn, dim3(512), dim3(256), 0, stream,
                     x, W1, gamma, beta, bmean, bvar, f);
  hipLaunchKernelGGL(k_sq, dim3(8192), dim3(256), 0, stream, f, sq);
  hipLaunchKernelGGL(k_wqk, dim3(8, 8), dim3(256), 0, stream, Wq, Wk, M);
  hipLaunchKernelGGL(k_qk, dim3(512), dim3(256), 0, stream, f, M, qk);
  for (int b = 0; b < B_; ++b) {
    for (int ro = 0; ro < NPTS; ro += CHUNK) {
      hipLaunchKernelGGL(k_dist, dim3(CHUNK / 64, 64), dim3(256), 0, stream,
                         f, sq, D, b, ro);
      hipLaunchKernelGGL(k_select, dim3(CHUNK), dim3(256), 0, stream,
                         D, f, qk, sv, b, ro);
    }
  }
  hipLaunchKernelGGL(k_final, dim3(8), dim3(256), 0, stream, sv, out);
}

// Round 6
// 1810.386 us; speedup vs baseline: 1.5016x; 1.1849x over previous
//
#include <hip/hip_runtime.h>
#include <math.h>

#define B_   8
#define CIN  1152
#define NPTS 4096
#define CH   128
#define KNN  32

// ---------------------------------------------------------------------------
// Kernel 1: 1x1 conv (W1 @ x) in FP64 + BN(inference, f64) + LeakyReLU(0.2)
// f = (float)f64. grid: 512 (b = bid&7, ntile = bid>>3), block 256
// [round-3 verbatim — exactly-rounded f is required by the fragile KNN
//  boundary point; both fp32 conv variants flipped it]
// ---------------------------------------------------------------------------
__global__ __launch_bounds__(256) void k_conv_bn(
    const float* __restrict__ x, const float* __restrict__ W1,
    const float* __restrict__ gamma, const float* __restrict__ beta,
    const float* __restrict__ bmean, const float* __restrict__ bvar,
    float* __restrict__ f)
{
  __shared__ float Wl[8][132];   // [k][c]
  __shared__ float Xl[8][64];    // [k][n]
  int bid = blockIdx.x;
  int b = bid & 7;
  int nbase = (bid >> 3) * 64;
  int t = threadIdx.x;
  int c0 = (t & 31) * 4, n0 = (t >> 5) * 8;
  double acc[4][8];
#pragma unroll
  for (int i = 0; i < 4; ++i)
#pragma unroll
    for (int j = 0; j < 8; ++j) acc[i][j] = 0.0;

  for (int k0 = 0; k0 < CIN; k0 += 8) {
    {
      int c = t >> 1, kp = (t & 1) * 4;
      float4 w4 = *(const float4*)&W1[(size_t)c * CIN + k0 + kp];
      Wl[kp + 0][c] = w4.x; Wl[kp + 1][c] = w4.y;
      Wl[kp + 2][c] = w4.z; Wl[kp + 3][c] = w4.w;
    }
    {
      int k = t >> 5, n = (t & 31) * 2;
      float2 x2 = *(const float2*)&x[((size_t)b * CIN + (k0 + k)) * NPTS + nbase + n];
      Xl[k][n] = x2.x; Xl[k][n + 1] = x2.y;
    }
    __syncthreads();
#pragma unroll
    for (int kk = 0; kk < 8; ++kk) {
      float4 a  = *(const float4*)&Wl[kk][c0];
      float4 b0 = *(const float4*)&Xl[kk][n0];
      float4 b1 = *(const float4*)&Xl[kk][n0 + 4];
      double av[4] = {(double)a.x, (double)a.y, (double)a.z, (double)a.w};
      double bv[8] = {(double)b0.x, (double)b0.y, (double)b0.z, (double)b0.w,
                      (double)b1.x, (double)b1.y, (double)b1.z, (double)b1.w};
#pragma unroll
      for (int i = 0; i < 4; ++i)
#pragma unroll
        for (int j = 0; j < 8; ++j) acc[i][j] = fma(av[i], bv[j], acc[i][j]);
    }
    __syncthreads();
  }
  double rs[4], gm[4], bt[4], mu[4];
#pragma unroll
  for (int i = 0; i < 4; ++i) {
    int c = c0 + i;
    rs[i] = 1.0 / sqrt((double)bvar[c] + 1e-5);
    gm[i] = (double)gamma[c]; bt[i] = (double)beta[c]; mu[i] = (double)bmean[c];
  }
#pragma unroll
  for (int j = 0; j < 8; ++j) {
    int n = nbase + n0 + j;
    float4 o;
    float* op = &o.x;
#pragma unroll
    for (int i = 0; i < 4; ++i) {
      double v = (acc[i][j] - mu[i]) * rs[i];
      v = v * gm[i] + bt[i];
      if (v < 0.0) v = 0.2 * v;
      op[i] = (float)v;
    }
    *(float4*)&f[((size_t)b * NPTS + n) * CH + c0] = o;
  }
}

// ---------------------------------------------------------------------------
// Kernel 2: sq[row] = sum_c f[row][c]^2 (fp32)  [round-3 verbatim]
// ---------------------------------------------------------------------------
__global__ __launch_bounds__(256) void k_sq(const float* __restrict__ f,
                                            float* __restrict__ sq)
{
  int row = blockIdx.x * 4 + (threadIdx.x >> 6);
  int lane = threadIdx.x & 63;
  float2 v = ((const float2*)f)[(size_t)row * 64 + lane];
  float s = v.x * v.x + v.y * v.y;
#pragma unroll
  for (int sft = 1; sft < 64; sft <<= 1) s += __shfl_xor(s, sft);
  if (lane == 0) sq[row] = s;
}

// ---------------------------------------------------------------------------
// Kernel 3: M[c][c'] = sum_o Wq[o][c] * Wk[o][c'] ; grid (8,8) x 256
// ---------------------------------------------------------------------------
__global__ __launch_bounds__(256) void k_wqk(const float* __restrict__ Wq,
                                             const float* __restrict__ Wk,
                                             float* __restrict__ M)
{
  __shared__ float Ql[128][17];
  __shared__ float Kl[128][17];
  int t = threadIdx.x;
  int cb = blockIdx.x * 16;
  int db = blockIdx.y * 16;
  {
    int o = t >> 1, h = (t & 1) * 8;
    float4 a = *(const float4*)&Wq[(size_t)o * CH + cb + h];
    float4 b = *(const float4*)&Wq[(size_t)o * CH + cb + h + 4];
    Ql[o][h + 0] = a.x; Ql[o][h + 1] = a.y; Ql[o][h + 2] = a.z; Ql[o][h + 3] = a.w;
    Ql[o][h + 4] = b.x; Ql[o][h + 5] = b.y; Ql[o][h + 6] = b.z; Ql[o][h + 7] = b.w;
    float4 c4 = *(const float4*)&Wk[(size_t)o * CH + db + h];
    float4 d4 = *(const float4*)&Wk[(size_t)o * CH + db + h + 4];
    Kl[o][h + 0] = c4.x; Kl[o][h + 1] = c4.y; Kl[o][h + 2] = c4.z; Kl[o][h + 3] = c4.w;
    Kl[o][h + 4] = d4.x; Kl[o][h + 5] = d4.y; Kl[o][h + 6] = d4.z; Kl[o][h + 7] = d4.w;
  }
  __syncthreads();
  int ci = t >> 4, cj = t & 15;
  float acc = 0.f;
#pragma unroll 8
  for (int o = 0; o < 128; ++o) acc = fmaf(Ql[o][ci], Kl[o][cj], acc);
  M[(size_t)(cb + ci) * CH + db + cj] = acc;
}

// ---------------------------------------------------------------------------
// Kernel 4: qk = f @ M  ([32768 x 128] x [128 x 128]) ; grid 512 x 256
// ---------------------------------------------------------------------------
__global__ __launch_bounds__(256) void k_qk(const float* __restrict__ f,
                                            const float* __restrict__ M,
                                            float* __restrict__ qk)
{
  __shared__ float Ft[128][68];      // [k][r], 64 rows
  __shared__ float Ml[128 * 128];    // [k][c']
  int t = threadIdx.x;
  size_t rbase = (size_t)blockIdx.x * 64;
  {
    int r = t & 63, cp = (t >> 6) * 32;
    for (int i = 0; i < 8; ++i) {
      int c = cp + i * 4;
      float4 v = *(const float4*)&f[(rbase + r) * CH + c];
      Ft[c][r] = v.x; Ft[c + 1][r] = v.y; Ft[c + 2][r] = v.z; Ft[c + 3][r] = v.w;
    }
  }
  {
    const float4* Mg = (const float4*)M;
    float4* Md = (float4*)Ml;
    for (int i = 0; i < 16; ++i) Md[t + 256 * i] = Mg[t + 256 * i];
  }
  __syncthreads();
  int r0 = (t >> 4) * 4, c0 = (t & 15) * 8;
  float acc[4][8];
#pragma unroll
  for (int i = 0; i < 4; ++i)
#pragma unroll
    for (int j = 0; j < 8; ++j) acc[i][j] = 0.f;
#pragma unroll 8
  for (int k = 0; k < 128; ++k) {
    float4 a  = *(const float4*)&Ft[k][r0];
    float4 b0 = *(const float4*)&Ml[k * 128 + c0];
    float4 b1 = *(const float4*)&Ml[k * 128 + c0 + 4];
    float av[4] = {a.x, a.y, a.z, a.w};
    float bv[8] = {b0.x, b0.y, b0.z, b0.w, b1.x, b1.y, b1.z, b1.w};
#pragma unroll
    for (int i = 0; i < 4; ++i)
#pragma unroll
      for (int j = 0; j < 8; ++j) acc[i][j] = fmaf(av[i], bv[j], acc[i][j]);
  }
#pragma unroll
  for (int i = 0; i < 4; ++i) {
    float4 o0 = {acc[i][0], acc[i][1], acc[i][2], acc[i][3]};
    float4 o1 = {acc[i][4], acc[i][5], acc[i][6], acc[i][7]};
    *(float4*)&qk[(rbase + r0 + i) * CH + c0]     = o0;
    *(float4*)&qk[(rbase + r0 + i) * CH + c0 + 4] = o1;
  }
}

// ---------------------------------------------------------------------------
// Kernel 5: distance GEMM -> D[chunk-local row][m] = (sq_n + sq_m) - 2 f_n.f_m
// [round-3 verbatim body — D's exact accumulation order is part of the
//  passing numeric recipe; only the grid got bigger]
// ---------------------------------------------------------------------------
__global__ __launch_bounds__(256) void k_dist(
    const float* __restrict__ f, const float* __restrict__ sq,
    float* __restrict__ D, int b, int rowoff)
{
  __shared__ float As[128][68];
  __shared__ float Bs[128][68];
  int t = threadIdx.x;
  int nb = rowoff + blockIdx.x * 64;      // batch-local row base
  int mb = blockIdx.y * 64;               // batch-local col base
  const float* fb = f + (size_t)b * NPTS * CH;
  {
    int r = t & 63, cq = (t >> 6) * 32;
    for (int i = 0; i < 8; ++i) {
      int c = cq + i * 4;
      float4 v = *(const float4*)&fb[(size_t)(nb + r) * CH + c];
      As[c][r] = v.x; As[c + 1][r] = v.y; As[c + 2][r] = v.z; As[c + 3][r] = v.w;
      float4 u = *(const float4*)&fb[(size_t)(mb + r) * CH + c];
      Bs[c][r] = u.x; Bs[c + 1][r] = u.y; Bs[c + 2][r] = u.z; Bs[c + 3][r] = u.w;
    }
  }
  __syncthreads();
  int r0 = (t >> 4) * 4, m0 = (t & 15) * 4;
  float acc[4][4];
#pragma unroll
  for (int i = 0; i < 4; ++i)
#pragma unroll
    for (int j = 0; j < 4; ++j) acc[i][j] = 0.f;
#pragma unroll 8
  for (int c = 0; c < 128; ++c) {
    float4 a  = *(const float4*)&As[c][r0];
    float4 bb = *(const float4*)&Bs[c][m0];
    float av[4] = {a.x, a.y, a.z, a.w};
    float bv[4] = {bb.x, bb.y, bb.z, bb.w};
#pragma unroll
    for (int i = 0; i < 4; ++i)
#pragma unroll
      for (int j = 0; j < 4; ++j) acc[i][j] = fmaf(av[i], bv[j], acc[i][j]);
  }
  float sqm[4];
#pragma unroll
  for (int j = 0; j < 4; ++j) sqm[j] = sq[(size_t)b * NPTS + mb + m0 + j];
#pragma unroll
  for (int i = 0; i < 4; ++i) {
    float sqn = sq[(size_t)b * NPTS + nb + r0 + i];
    float4 o;
    o.x = (sqn + sqm[0]) - 2.f * acc[i][0];
    o.y = (sqn + sqm[1]) - 2.f * acc[i][1];
    o.z = (sqn + sqm[2]) - 2.f * acc[i][2];
    o.w = (sqn + sqm[3]) - 2.f * acc[i][3];
    int rloc = blockIdx.x * 64 + r0 + i;    // chunk-local row
    *(float4*)&D[(size_t)rloc * NPTS + mb + m0] = o;
  }
}

// ---------------------------------------------------------------------------
// Kernel 6: radix-select exact top-32. Set = {keys < thr_key} ∪ lowest-index
// {keys == thr_key} — identical to stable top_k's set given identical keys.
// + attention + std-over-K. [round-5 verbatim] grid = chunk, block 256.
// ---------------------------------------------------------------------------
__device__ __forceinline__ unsigned int sortkey(float x) {
  unsigned int u = __float_as_uint(x);
  return (u & 0x80000000u) ? ~u : (u | 0x80000000u);
}

__global__ __launch_bounds__(256) void k_select(
    const float* __restrict__ D, const float* __restrict__ f,
    const float* __restrict__ qk, float* __restrict__ sv,
    int b, int rowoff)
{
  __shared__ unsigned int keys[NPTS];      // 16 KB sortable keys
  __shared__ unsigned int hist[256];
  __shared__ unsigned int wsum[4];
  __shared__ unsigned int eqw[4];
  __shared__ unsigned int sh_bucket, sh_excl, nkept;
  __shared__ int   kept[KNN];
  __shared__ float qkl[CH];
  __shared__ float fc[CH];
  __shared__ float eng[KNN];

  int t = threadIdx.x;
  int row = rowoff + blockIdx.x;            // batch-local row
  const float* fb = f + (size_t)b * NPTS * CH;

  {
    const float4* Dp = (const float4*)(D + (size_t)blockIdx.x * NPTS);
#pragma unroll
    for (int i = 0; i < 4; ++i) {
      float4 v = Dp[t + 256 * i];
      uint4 u;
      u.x = sortkey(v.x); u.y = sortkey(v.y);
      u.z = sortkey(v.z); u.w = sortkey(v.w);
      ((uint4*)keys)[t + 256 * i] = u;
    }
  }
  if (t == 0) nkept = 0;
  if (t < 32) {
    ((float4*)qkl)[t] = ((const float4*)(qk + ((size_t)b * NPTS + row) * CH))[t];
  } else if (t < 64) {
    ((float4*)fc)[t - 32] = ((const float4*)(fb + (size_t)row * CH))[t - 32];
  }
  __syncthreads();

  // 4-pass 8-bit radix select: find exact key of rank KNN (1-based)
  unsigned int prefix = 0;
  unsigned int target = KNN;
  unsigned int cnt_less = 0;
  for (int pass = 0; pass < 4; ++pass) {
    int shift = 24 - pass * 8;
    hist[t] = 0;
    __syncthreads();
#pragma unroll
    for (int i = 0; i < 16; ++i) {
      unsigned int k = keys[t + 256 * i];
      bool m = (pass == 0) || ((k >> (shift + 8)) == prefix);
      if (m) atomicAdd(&hist[(k >> shift) & 255u], 1u);
    }
    __syncthreads();
    unsigned int v = hist[t];
    unsigned int sc = v;
#pragma unroll
    for (int d = 1; d < 64; d <<= 1) {
      unsigned int nn = __shfl_up(sc, d);
      if ((t & 63) >= d) sc += nn;
    }
    if ((t & 63) == 63) wsum[t >> 6] = sc;
    __syncthreads();
    unsigned int wo = 0;
#pragma unroll
    for (int w = 0; w < 4; ++w) wo += (w < (t >> 6)) ? wsum[w] : 0u;
    unsigned int incl = sc + wo;
    unsigned int excl = incl - v;
    if (excl < target && target <= incl) { sh_bucket = (unsigned int)t; sh_excl = excl; }
    __syncthreads();
    prefix = (prefix << 8) | sh_bucket;
    target -= sh_excl;
    cnt_less += sh_excl;
    __syncthreads();
  }
  unsigned int thr_key = prefix;

  // compact strictly-less (arbitrary slot order; set semantics)
#pragma unroll
  for (int i = 0; i < 16; ++i) {
    int idx = t + 256 * i;
    if (keys[idx] < thr_key) {
      unsigned int p = atomicAdd(&nkept, 1u);
      kept[p] = idx;
    }
  }
  // fill remaining slots with ==thr_key elements in increasing index order
  {
    unsigned int eqloc = 0;
#pragma unroll
    for (int j = 0; j < 16; ++j) eqloc += (keys[t * 16 + j] == thr_key) ? 1u : 0u;
    unsigned int esc = eqloc;
#pragma unroll
    for (int d = 1; d < 64; d <<= 1) {
      unsigned int nn = __shfl_up(esc, d);
      if ((t & 63) >= d) esc += nn;
    }
    if ((t & 63) == 63) eqw[t >> 6] = esc;
    __syncthreads();
    unsigned int ewo = 0;
#pragma unroll
    for (int w = 0; w < 4; ++w) ewo += (w < (t >> 6)) ? eqw[w] : 0u;
    unsigned int slot = cnt_less + (esc + ewo - eqloc);
#pragma unroll
    for (int j = 0; j < 16; ++j) {
      if (keys[t * 16 + j] == thr_key) {
        if (slot < KNN) kept[slot] = t * 16 + j;
        slot++;
      }
    }
  }
  __syncthreads();

  // energies: e_k = qk_n . (f_m - f_n) / sqrt(128)
  {
    int kk = t >> 3, lg = t & 7;
    int mg = kept[kk];
    const float* fm = fb + (size_t)mg * CH;
    float dd = 0.f, ds = 0.f;
#pragma unroll
    for (int i = 0; i < 4; ++i) {
      float4 qv = *(const float4*)&qkl[lg * 16 + i * 4];
      float4 vm = *(const float4*)&fm[lg * 16 + i * 4];
      float4 vc = *(const float4*)&fc[lg * 16 + i * 4];
      dd = fmaf(qv.x, vm.x, dd); dd = fmaf(qv.y, vm.y, dd);
      dd = fmaf(qv.z, vm.z, dd); dd = fmaf(qv.w, vm.w, dd);
      ds = fmaf(qv.x, vc.x, ds); ds = fmaf(qv.y, vc.y, ds);
      ds = fmaf(qv.z, vc.z, ds); ds = fmaf(qv.w, vc.w, ds);
    }
#pragma unroll
    for (int m = 1; m < 8; m <<= 1) { dd += __shfl_xor(dd, m); ds += __shfl_xor(ds, m); }
    if (lg == 0) eng[kk] = (dd - ds) * 0.08838834764831845f;
  }
  __syncthreads();

  // softmax over K + biased std over K (lanes 0..31 of wave 0)
  if (t < 64) {
    float e = (t < 32) ? eng[t] : -INFINITY;
    float mx = e;
#pragma unroll
    for (int m = 1; m < 32; m <<= 1) mx = fmaxf(mx, __shfl_xor(mx, m));
    float ex = (t < 32) ? expf(e - mx) : 0.f;
    float sm = ex;
#pragma unroll
    for (int m = 1; m < 32; m <<= 1) sm += __shfl_xor(sm, m);
    float a  = (t < 32) ? (ex / sm) : 0.f;
    float sa = a;
#pragma unroll
    for (int m = 1; m < 32; m <<= 1) sa += __shfl_xor(sa, m);
    float mean = sa * (1.f / 32.f);
    float dv = (t < 32) ? (a - mean) : 0.f;
    float vr = dv * dv;
#pragma unroll
    for (int m = 1; m < 32; m <<= 1) vr += __shfl_xor(vr, m);
    if (t == 0) sv[(size_t)b * NPTS + row] = sqrtf(vr * (1.f / 32.f));
  }
}

// ---------------------------------------------------------------------------
// Kernel 7: per-cloud standardize (ddof=1) + modified sigmoid; grid 8 x 256
// ---------------------------------------------------------------------------
__global__ __launch_bounds__(256) void k_final(const float* __restrict__ s,
                                               float* __restrict__ out)
{
  __shared__ float red[4];
  int b = blockIdx.x, t = threadIdx.x;
  const float4* sp = (const float4*)(s + (size_t)b * NPTS);
  float4* op = (float4*)(out + (size_t)b * NPTS);
  float4 vs[4];
  float loc = 0.f;
#pragma unroll
  for (int i = 0; i < 4; ++i) {
    vs[i] = sp[t + 256 * i];
    loc += vs[i].x + vs[i].y + vs[i].z + vs[i].w;
  }
#pragma unroll
  for (int sft = 1; sft < 64; sft <<= 1) loc += __shfl_xor(loc, sft);
  if ((t & 63) == 0) red[t >> 6] = loc;
  __syncthreads();
  float meanv = (red[0] + red[1] + red[2] + red[3]) * (1.f / 4096.f);
  __syncthreads();
  float loc2 = 0.f;
#pragma unroll
  for (int i = 0; i < 4; ++i) {
    float dx = vs[i].x - meanv, dy = vs[i].y - meanv;
    float dz = vs[i].z - meanv, dw = vs[i].w - meanv;
    loc2 += dx * dx + dy * dy + dz * dz + dw * dw;
  }
#pragma unroll
  for (int sft = 1; sft < 64; sft <<= 1) loc2 += __shfl_xor(loc2, sft);
  if ((t & 63) == 0) red[t >> 6] = loc2;
  __syncthreads();
  float var = (red[0] + red[1] + red[2] + red[3]) * (1.f / 4095.f);
  float rstd = rsqrtf(var);
  const float L20 = 4.3219280948873623f;  // log2(20)
#pragma unroll
  for (int i = 0; i < 4; ++i) {
    float4 v = vs[i], o;
    o.x = 1.f / (1.f + exp2f(-(v.x - meanv) * rstd * L20));
    o.y = 1.f / (1.f + exp2f(-(v.y - meanv) * rstd * L20));
    o.z = 1.f / (1.f + exp2f(-(v.z - meanv) * rstd * L20));
    o.w = 1.f / (1.f + exp2f(-(v.w - meanv) * rstd * L20));
    op[t + 256 * i] = o;
  }
}

// ---------------------------------------------------------------------------
extern "C" void kernel_launch(void* const* d_in, const int* in_sizes, int n_in,
                              void* d_out, int out_size, void* d_ws, size_t ws_size,
                              hipStream_t stream)
{
  const float* x     = (const float*)d_in[0];
  const float* W1    = (const float*)d_in[1];
  const float* gamma = (const float*)d_in[2];
  const float* beta  = (const float*)d_in[3];
  const float* bmean = (const float*)d_in[4];
  const float* bvar  = (const float*)d_in[5];
  const float* Wq    = (const float*)d_in[6];
  const float* Wk    = (const float*)d_in[7];
  float* out = (float*)d_out;

  float* f  = (float*)d_ws;                               // 16 MB
  float* qk = f  + (size_t)B_ * NPTS * CH;                // 16 MB
  float* sq = qk + (size_t)B_ * NPTS * CH;                // 128 KB
  float* sv = sq + (size_t)B_ * NPTS;                     // 128 KB
  float* M  = sv + (size_t)B_ * NPTS;                     // 64 KB
  float* D  = M  + (size_t)CH * CH;                       // chunk*4096*4 B

  // pick the largest chunk that fits the workspace (deterministic: ws_size
  // is constant across calls). 4096 -> 64 MB D; 2048 -> 32 MB; 1024 -> 16 MB.
  size_t fixed_bytes = (size_t)((char*)D - (char*)d_ws);
  size_t avail = (ws_size > fixed_bytes) ? (ws_size - fixed_bytes) : 0;
  int chunk = 1024;
  if (avail >= (size_t)4096 * NPTS * 4) chunk = 4096;
  else if (avail >= (size_t)2048 * NPTS * 4) chunk = 2048;

  hipLaunchKernelGGL(k_conv_bn, dim3(512), dim3(256), 0, stream,
                     x, W1, gamma, beta, bmean, bvar, f);
  hipLaunchKernelGGL(k_sq, dim3(8192), dim3(256), 0, stream, f, sq);
  hipLaunchKernelGGL(k_wqk, dim3(8, 8), dim3(256), 0, stream, Wq, Wk, M);
  hipLaunchKernelGGL(k_qk, dim3(512), dim3(256), 0, stream, f, M, qk);
  for (int b = 0; b < B_; ++b) {
    for (int ro = 0; ro < NPTS; ro += chunk) {
      hipLaunchKernelGGL(k_dist, dim3(chunk / 64, 64), dim3(256), 0, stream,
                         f, sq, D, b, ro);
      hipLaunchKernelGGL(k_select, dim3(chunk), dim3(256), 0, stream,
                         D, f, qk, sv, b, ro);
    }
  }
  hipLaunchKernelGGL(k_final, dim3(8), dim3(256), 0, stream, sv, out);
}